// Round 6
// baseline (913.225 us; speedup 1.0000x reference)
//
#include <hip/hip_runtime.h>
#include <hip/hip_bf16.h>

// Show-Attend-Tell attention. B=128, P=196, E=2048, H=1024, A=1024.
// ESTABLISHED: inputs fp32 (round 4). Round 5's bit-identical absmax across
// two different scores kernels => outputs are FP32 (reference dtype; harness
// contract "else float*"), and the MFMA GEMM was already numerically correct.
// Round 6: same pipeline, fp32 in/out everywhere. Intermediates inside d_out
// (fp32 elems, 287232 total = 1,148,928 B):
//   bytes [0      : 524288)  att2' fp32 [B][A]   (dead after GEMM)
//   bytes [524288 : 624640)  scores fp32 [M]     (dead after softmax)
//   elems [262144 : 287232)  alpha fp32 (final)
//   elems [0      : 262144)  context fp32 (final, written LAST by k_context)

#define B_   128
#define P_   196
#define E_   2048
#define H_   1024
#define A_   1024
#define M_   (B_ * P_)   // 25088 = 196 * 128

typedef __bf16 bf16x8 __attribute__((ext_vector_type(8)));
typedef float f32x4 __attribute__((ext_vector_type(4)));

__device__ __forceinline__ bf16x8 cvt8(const float* p) {
    const float4 a = *(const float4*)p;
    const float4 b = *(const float4*)(p + 4);
    bf16x8 r;
    r[0] = (__bf16)a.x; r[1] = (__bf16)a.y; r[2] = (__bf16)a.z; r[3] = (__bf16)a.w;
    r[4] = (__bf16)b.x; r[5] = (__bf16)b.y; r[6] = (__bf16)b.z; r[7] = (__bf16)b.w;
    return r;
}

// ---------------------------------------------------------------------------
// K1: zero scores; att2p[b][a] = b_enc[a] + b_dec[a] + sum_h dh[b][h]*W_dec[h][a]
// ---------------------------------------------------------------------------
__global__ __launch_bounds__(256) void k_att2(
    const float* __restrict__ dh, const float* __restrict__ wdec,
    const float* __restrict__ benc, const float* __restrict__ bdec,
    float* __restrict__ scores, float* __restrict__ att2p) {
    const int b = blockIdx.x, t = threadIdx.x;
    const int gi = b * 256 + t;
    if (gi < M_) scores[gi] = 0.f;          // zero before GEMM's atomicAdd
    __shared__ float hs[H_];
    for (int i = t; i < H_; i += 256) hs[i] = dh[(size_t)b * H_ + i];
    __syncthreads();
    const int a0 = t * 4;
    const float4 be = *(const float4*)(benc + a0);
    const float4 bd = *(const float4*)(bdec + a0);
    float ax = be.x + bd.x, ay = be.y + bd.y;
    float az = be.z + bd.z, aw = be.w + bd.w;
#pragma unroll 4
    for (int h = 0; h < H_; ++h) {
        const float4 w = *(const float4*)(wdec + (size_t)h * A_ + a0);
        const float hv = hs[h];
        ax += hv * w.x; ay += hv * w.y; az += hv * w.z; aw += hv * w.w;
    }
    float4 o; o.x = ax; o.y = ay; o.z = az; o.w = aw;
    *(float4*)(att2p + (size_t)b * A_ + a0) = o;
}

// ---------------------------------------------------------------------------
// K2: fused GEMM(att1, bf16 MFMA) + bias + relu + W_full row-reduce ->
// atomicAdd into scores[M]. C-tile 128x128, BK=64, 4 waves of 4x4
// 16x16x32-bf16 frags. W_enc consumed in native [E][A]=[k][n] layout; B tile
// transposed into LDS during staging with XOR swizzle:
//   elem (n,k) at Bs[n*64 + gp*8 + (k&7)], gp = ((k>>3) ^ (n>>3) ^ n) & 7
// fp32 global loads, converted to bf16 in-register before LDS.
// ---------------------------------------------------------------------------
__global__ __launch_bounds__(256, 2) void k_gemm_scores(
    const float* __restrict__ Am,       // enc   [M_][E_] fp32
    const float* __restrict__ Wb,       // W_enc [E_][A_] fp32
    const float* __restrict__ att2p,    // [B_][A_] fp32
    const float* __restrict__ wfull,    // [A_] fp32
    float* __restrict__ scores) {       // [M_] fp32
    __shared__ __align__(16) __bf16 As[128 * 72];
    __shared__ __align__(16) __bf16 Bs[128 * 64];
    __shared__ float red[2][128];

    const int t = threadIdx.x;
    const int lane = t & 63;
    const int wave = t >> 6;
    const int wm = wave >> 1, wn = wave & 1;
    const int q = lane >> 4, r = lane & 15;
    const int bn = blockIdx.x, bm = blockIdx.y;
    const int m0 = bm * 128, n0 = bn * 128;

    const int srow = t >> 3;   // A staging: 0..31
    const int sseg = t & 7;    //            0..7 (8-elem segs of 64-elem row)
    const int kb = t >> 2;     // B staging: k row 0..63
    const int s0 = t & 3;      //            base n-seg

    f32x4 acc[4][4] = {};

    for (int kk = 0; kk < E_; kk += 64) {
#pragma unroll
        for (int i = 0; i < 4; ++i) {   // A: [m][k] k-contiguous, stride 72
            const int row = srow + i * 32;
            *(bf16x8*)&As[row * 72 + sseg * 8] =
                cvt8(Am + (size_t)(m0 + row) * E_ + kk + sseg * 8);
        }
        {   // B: transpose-scatter with swizzle
            const int g = kb >> 3, kl = kb & 7;
#pragma unroll
            for (int i = 0; i < 4; ++i) {
                const int seg = s0 + 4 * i;  // 0..15
                const bf16x8 e = cvt8(Wb + (size_t)(kk + kb) * A_ + n0 + seg * 8);
#pragma unroll
                for (int j = 0; j < 8; ++j) {
                    const int n = seg * 8 + j;
                    const int gp = (g ^ (n >> 3) ^ n) & 7;
                    Bs[n * 64 + gp * 8 + kl] = e[j];
                }
            }
        }
        __syncthreads();
#pragma unroll
        for (int ks = 0; ks < 2; ++ks) {
            bf16x8 af[4], bfv[4];
#pragma unroll
            for (int f = 0; f < 4; ++f)   // A frag: m=lane&15, k=q*8+j
                af[f] = *(const bf16x8*)&As[(wm * 64 + f * 16 + r) * 72 +
                                            ks * 32 + q * 8];
#pragma unroll
            for (int f = 0; f < 4; ++f) { // B frag: n=lane&15, k=q*8+j
                const int nf = wn * 64 + f * 16 + r;
                const int gb = ((ks * 4 + q) ^ (nf >> 3) ^ nf) & 7;
                bfv[f] = *(const bf16x8*)&Bs[nf * 64 + gb * 8];
            }
#pragma unroll
            for (int fm = 0; fm < 4; ++fm)
#pragma unroll
                for (int fn = 0; fn < 4; ++fn)
                    acc[fm][fn] = __builtin_amdgcn_mfma_f32_16x16x32_bf16(
                        af[fm], bfv[fn], acc[fm][fn], 0, 0, 0);
        }
        __syncthreads();
    }

    // Epilogue. C/D layout: col(n) = lane&15, row(m) = q*4 + reg.
    float psum[4][4];
#pragma unroll
    for (int fm = 0; fm < 4; ++fm) {
#pragma unroll
        for (int i = 0; i < 4; ++i) {
            const int row_g = m0 + wm * 64 + fm * 16 + q * 4 + i;
            const unsigned bidx = (unsigned)row_g / 196u;
            const float* a2 = att2p + (size_t)bidx * A_ + n0 + wn * 64;
            float s = 0.f;
#pragma unroll
            for (int fn = 0; fn < 4; ++fn) {
                const int cl = fn * 16 + r;
                float v = acc[fm][fn][i] + a2[cl];
                v = fmaxf(v, 0.f);
                s += v * wfull[n0 + wn * 64 + cl];
            }
            psum[fm][i] = s;
        }
    }
#pragma unroll
    for (int fm = 0; fm < 4; ++fm)
#pragma unroll
        for (int i = 0; i < 4; ++i) {
            float v = psum[fm][i];
            v += __shfl_xor(v, 1);
            v += __shfl_xor(v, 2);
            v += __shfl_xor(v, 4);
            v += __shfl_xor(v, 8);
            if (r == 0) red[wn][wm * 64 + fm * 16 + q * 4 + i] = v;
        }
    __syncthreads();
    if (t < 128) atomicAdd(&scores[m0 + t], red[0][t] + red[1][t]);
}

// ---------------------------------------------------------------------------
// K3: softmax over P=196 per batch; alpha (fp32) -> d_out elems [262144, ...).
// ---------------------------------------------------------------------------
__global__ __launch_bounds__(256) void k_softmax(
    const float* __restrict__ scores, float* __restrict__ out) {
    const int b = blockIdx.x;
    const int t = threadIdx.x;
    __shared__ float sm[256];
    const bool act = t < P_;
    const float val = act ? scores[b * P_ + t] : 0.f;
    sm[t] = act ? val : -1e30f;
    __syncthreads();
    for (int off = 128; off > 0; off >>= 1) {
        if (t < off) sm[t] = fmaxf(sm[t], sm[t + off]);
        __syncthreads();
    }
    const float mx = sm[0];
    __syncthreads();
    const float e = act ? __expf(val - mx) : 0.f;
    sm[t] = e;
    __syncthreads();
    for (int off = 128; off > 0; off >>= 1) {
        if (t < off) sm[t] = sm[t] + sm[t + off];
        __syncthreads();
    }
    const float inv = 1.0f / sm[0];
    if (act) out[(size_t)B_ * E_ + b * P_ + t] = e * inv;
}

// ---------------------------------------------------------------------------
// K4: context[b][e] = sum_p alpha[b][p] * enc[b][p][e]  (all fp32)
// Overwrites the att2p/scores staging bytes (dead by now).
// ---------------------------------------------------------------------------
__global__ __launch_bounds__(256) void k_context(
    const float* __restrict__ enc, float* __restrict__ out) {
    const int b = blockIdx.y;
    const int e0 = blockIdx.x * 1024 + threadIdx.x * 4;
    __shared__ float al[P_];
    if (threadIdx.x < P_)
        al[threadIdx.x] = out[(size_t)B_ * E_ + b * P_ + threadIdx.x];
    __syncthreads();
    float ax = 0.f, ay = 0.f, az = 0.f, aw = 0.f;
    const float* base = enc + (size_t)b * P_ * E_ + e0;
#pragma unroll 2
    for (int p = 0; p < P_; ++p) {
        const float4 v = *(const float4*)(base + (size_t)p * E_);
        const float ap = al[p];
        ax += ap * v.x; ay += ap * v.y; az += ap * v.z; aw += ap * v.w;
    }
    float4 sv; sv.x = ax; sv.y = ay; sv.z = az; sv.w = aw;
    *(float4*)(out + (size_t)b * E_ + e0) = sv;
}

// ---------------------------------------------------------------------------
extern "C" void kernel_launch(void* const* d_in, const int* in_sizes, int n_in,
                              void* d_out, int out_size, void* d_ws,
                              size_t ws_size, hipStream_t stream) {
    const float* enc   = (const float*)d_in[0];
    const float* dh    = (const float*)d_in[1];
    const float* wenc  = (const float*)d_in[2];
    const float* benc  = (const float*)d_in[3];
    const float* wdec  = (const float*)d_in[4];
    const float* bdec  = (const float*)d_in[5];
    const float* wfull = (const float*)d_in[6];
    // d_in[7] = b_full: softmax shift-invariant, unused
    float* out = (float*)d_out;

    // Intermediates inside d_out (fp32):
    float* att2p  = out;                              // bytes [0, 524288)
    float* scores = (float*)((char*)d_out + 524288);  // bytes [524288, 624640)

    k_att2<<<B_, 256, 0, stream>>>(dh, wdec, benc, bdec, scores, att2p);
    k_gemm_scores<<<dim3(8, M_ / 128), 256, 0, stream>>>(enc, wenc, att2p,
                                                         wfull, scores);
    k_softmax<<<B_, 256, 0, stream>>>(scores, out);
    k_context<<<dim3(2, B_), 256, 0, stream>>>(enc, out);
}

// Round 7
// 683.947 us; speedup vs baseline: 1.3352x; 1.3352x over previous
//
#include <hip/hip_runtime.h>
#include <hip/hip_bf16.h>

// Show-Attend-Tell attention. B=128, P=196, E=2048, H=1024, A=1024.
// fp32 in / fp32 out (established round 6; passed absmax 1.95e-3).
// Round 7: gemm 2 n-tiles/block + b64-pair B staging; att2 re-grid; context MLP.
// Intermediates inside d_out (fp32, 287232 elems total):
//   bytes [0      : 524288)  att2' fp32 [B][A]   (dead after GEMM)
//   bytes [524288 : 624640)  scores fp32 [M]     (dead after softmax)
//   elems [262144 : 287232)  alpha fp32 (final)
//   elems [0      : 262144)  context fp32 (final, written LAST by k_context)

#define B_   128
#define P_   196
#define E_   2048
#define H_   1024
#define A_   1024
#define M_   (B_ * P_)   // 25088 = 196 * 128

typedef __bf16 bf16x8 __attribute__((ext_vector_type(8)));
typedef __bf16 bf16x4 __attribute__((ext_vector_type(4)));
typedef float f32x4 __attribute__((ext_vector_type(4)));

__device__ __forceinline__ bf16x8 cvt8(const float* p) {
    const float4 a = *(const float4*)p;
    const float4 b = *(const float4*)(p + 4);
    bf16x8 r;
    r[0] = (__bf16)a.x; r[1] = (__bf16)a.y; r[2] = (__bf16)a.z; r[3] = (__bf16)a.w;
    r[4] = (__bf16)b.x; r[5] = (__bf16)b.y; r[6] = (__bf16)b.z; r[7] = (__bf16)b.w;
    return r;
}

// ---------------------------------------------------------------------------
// K1: zero scores; att2p[b][a] = b_enc[a]+b_dec[a]+sum_h dh[b][h]*W_dec[h][a]
// Grid (8 a-chunks of 128, 128 b). Thread: one a, half of H. Coalesced
// W_dec column loads (128 consecutive a per load), unroll 8 for MLP.
// ---------------------------------------------------------------------------
__global__ __launch_bounds__(256) void k_att2(
    const float* __restrict__ dh, const float* __restrict__ wdec,
    const float* __restrict__ benc, const float* __restrict__ bdec,
    float* __restrict__ scores, float* __restrict__ att2p) {
    const int b = blockIdx.y;
    const int a0 = blockIdx.x * 128;
    const int t = threadIdx.x;
    const int bid = blockIdx.y * 8 + blockIdx.x;
    const int gi = bid * 256 + t;
    if (gi < M_) scores[gi] = 0.f;          // zero before GEMM's atomicAdd
    __shared__ float hs[H_];
    __shared__ float red[256];
    for (int i = t; i < H_; i += 256) hs[i] = dh[(size_t)b * H_ + i];
    __syncthreads();
    const int a = a0 + (t & 127);
    const int h0 = (t >> 7) * 512;
    float acc = 0.f;
#pragma unroll 8
    for (int h = 0; h < 512; ++h)
        acc += hs[h0 + h] * wdec[(size_t)(h0 + h) * A_ + a];
    red[t] = acc;
    __syncthreads();
    if (t < 128)
        att2p[(size_t)b * A_ + a0 + t] =
            red[t] + red[t + 128] + benc[a0 + t] + bdec[a0 + t];
}

// ---------------------------------------------------------------------------
// K2: fused GEMM(att1, bf16 MFMA) + bias + relu + W_full row-reduce ->
// atomicAdd into scores[M]. C-tile 128 m x 256 n, BK=64. 4 waves: wm=wave>>1
// (64 m), wn=wave&1 (128 n); each wave 4x8 frags of 16x16x32-bf16.
// B tile (256 n x 64 k) transposed into LDS with XOR swizzle:
//   elem (n,k) at Bs[n*64 + gp*8 + (k&7)], gp = ((k>>3) ^ (n>>3) ^ n) & 7
// Staged as PAIRED writes: thread owns 4 consecutive k x 16 n -> 16 b64 ops.
// ---------------------------------------------------------------------------
__global__ __launch_bounds__(256, 2) void k_gemm_scores(
    const float* __restrict__ Am,       // enc   [M_][E_] fp32
    const float* __restrict__ Wb,       // W_enc [E_][A_] fp32
    const float* __restrict__ att2p,    // [B_][A_] fp32
    const float* __restrict__ wfull,    // [A_] fp32
    float* __restrict__ scores) {       // [M_] fp32
    __shared__ __align__(16) __bf16 As[128 * 72];
    __shared__ __align__(16) __bf16 Bs[256 * 64];
    __shared__ float red[2][128];

    const int t = threadIdx.x;
    const int lane = t & 63;
    const int wave = t >> 6;
    const int wm = wave >> 1, wn = wave & 1;
    const int q = lane >> 4, r = lane & 15;
    const int bn = blockIdx.x, bm = blockIdx.y;
    const int m0 = bm * 128, n0 = bn * 256;

    const int srow = t >> 3;        // A staging row 0..31
    const int sseg = t & 7;         // A staging 8-elem seg
    const int k0 = (t & 15) * 4;    // B staging: 4 consecutive k
    const int kq = k0 >> 3;         //   8-group index
    const int kl = k0 & 7;          //   0 or 4 within group
    const int nb = (t >> 4) * 16;   // B staging: 16-n chunk base

    f32x4 acc[4][8] = {};

    for (int kk = 0; kk < E_; kk += 64) {
#pragma unroll
        for (int i = 0; i < 4; ++i) {   // A: [m][k] k-contiguous, stride 72
            const int row = srow + i * 32;
            *(bf16x8*)&As[row * 72 + sseg * 8] =
                cvt8(Am + (size_t)(m0 + row) * E_ + kk + sseg * 8);
        }
        // B: 4 k-rows x 16 n per thread, two 8-n halves to cap registers
#pragma unroll
        for (int half = 0; half < 2; ++half) {
            const int jb = half * 8;
            float ldv[4][8];
#pragma unroll
            for (int dk = 0; dk < 4; ++dk) {
                const float4 a = *(const float4*)(
                    Wb + (size_t)(kk + k0 + dk) * A_ + n0 + nb + jb);
                const float4 b = *(const float4*)(
                    Wb + (size_t)(kk + k0 + dk) * A_ + n0 + nb + jb + 4);
                ldv[dk][0] = a.x; ldv[dk][1] = a.y;
                ldv[dk][2] = a.z; ldv[dk][3] = a.w;
                ldv[dk][4] = b.x; ldv[dk][5] = b.y;
                ldv[dk][6] = b.z; ldv[dk][7] = b.w;
            }
#pragma unroll
            for (int j = 0; j < 8; ++j) {
                const int n = nb + jb + j;
                const int gp = (kq ^ (n >> 3) ^ n) & 7;
                bf16x4 wv;
                wv[0] = (__bf16)ldv[0][j]; wv[1] = (__bf16)ldv[1][j];
                wv[2] = (__bf16)ldv[2][j]; wv[3] = (__bf16)ldv[3][j];
                *(bf16x4*)&Bs[n * 64 + gp * 8 + kl] = wv;
            }
        }
        __syncthreads();
#pragma unroll
        for (int ks = 0; ks < 2; ++ks) {
            bf16x8 af[4], bfv[8];
#pragma unroll
            for (int f = 0; f < 4; ++f)   // A frag: m=lane&15, k=q*8+j
                af[f] = *(const bf16x8*)&As[(wm * 64 + f * 16 + r) * 72 +
                                            ks * 32 + q * 8];
#pragma unroll
            for (int f = 0; f < 8; ++f) { // B frag: n=lane&15, k=q*8+j
                const int nf = wn * 128 + f * 16 + r;
                const int gb = ((ks * 4 + q) ^ (nf >> 3) ^ nf) & 7;
                bfv[f] = *(const bf16x8*)&Bs[nf * 64 + gb * 8];
            }
#pragma unroll
            for (int fm = 0; fm < 4; ++fm)
#pragma unroll
                for (int fn = 0; fn < 8; ++fn)
                    acc[fm][fn] = __builtin_amdgcn_mfma_f32_16x16x32_bf16(
                        af[fm], bfv[fn], acc[fm][fn], 0, 0, 0);
        }
        __syncthreads();
    }

    // Epilogue. C/D layout: col(n) = lane&15, row(m) = q*4 + reg.
    float psum[4][4];
#pragma unroll
    for (int fm = 0; fm < 4; ++fm) {
#pragma unroll
        for (int i = 0; i < 4; ++i) {
            const int row_g = m0 + wm * 64 + fm * 16 + q * 4 + i;
            const unsigned bidx = (unsigned)row_g / 196u;
            const float* a2 = att2p + (size_t)bidx * A_ + n0 + wn * 128;
            const float* wf = wfull + n0 + wn * 128;
            float s = 0.f;
#pragma unroll
            for (int fn = 0; fn < 8; ++fn) {
                const int cl = fn * 16 + r;
                float v = acc[fm][fn][i] + a2[cl];
                v = fmaxf(v, 0.f);
                s += v * wf[cl];
            }
            psum[fm][i] = s;
        }
    }
#pragma unroll
    for (int fm = 0; fm < 4; ++fm)
#pragma unroll
        for (int i = 0; i < 4; ++i) {
            float v = psum[fm][i];
            v += __shfl_xor(v, 1);
            v += __shfl_xor(v, 2);
            v += __shfl_xor(v, 4);
            v += __shfl_xor(v, 8);
            if (r == 0) red[wn][wm * 64 + fm * 16 + q * 4 + i] = v;
        }
    __syncthreads();
    if (t < 128) atomicAdd(&scores[m0 + t], red[0][t] + red[1][t]);
}

// ---------------------------------------------------------------------------
// K3: softmax over P=196 per batch; alpha (fp32) -> d_out elems [262144,...).
// ---------------------------------------------------------------------------
__global__ __launch_bounds__(256) void k_softmax(
    const float* __restrict__ scores, float* __restrict__ out) {
    const int b = blockIdx.x;
    const int t = threadIdx.x;
    __shared__ float sm[256];
    const bool act = t < P_;
    const float val = act ? scores[b * P_ + t] : 0.f;
    sm[t] = act ? val : -1e30f;
    __syncthreads();
    for (int off = 128; off > 0; off >>= 1) {
        if (t < off) sm[t] = fmaxf(sm[t], sm[t + off]);
        __syncthreads();
    }
    const float mx = sm[0];
    __syncthreads();
    const float e = act ? __expf(val - mx) : 0.f;
    sm[t] = e;
    __syncthreads();
    for (int off = 128; off > 0; off >>= 1) {
        if (t < off) sm[t] = sm[t] + sm[t + off];
        __syncthreads();
    }
    const float inv = 1.0f / sm[0];
    if (act) out[(size_t)B_ * E_ + b * P_ + t] = e * inv;
}

// ---------------------------------------------------------------------------
// K4: context[b][e] = sum_p alpha[b][p] * enc[b][p][e]  (all fp32)
// unroll 14 (196 = 14*14) for memory-level parallelism.
// ---------------------------------------------------------------------------
__global__ __launch_bounds__(256) void k_context(
    const float* __restrict__ enc, float* __restrict__ out) {
    const int b = blockIdx.y;
    const int e0 = blockIdx.x * 1024 + threadIdx.x * 4;
    __shared__ float al[P_];
    if (threadIdx.x < P_)
        al[threadIdx.x] = out[(size_t)B_ * E_ + b * P_ + threadIdx.x];
    __syncthreads();
    float ax = 0.f, ay = 0.f, az = 0.f, aw = 0.f;
    const float* base = enc + (size_t)b * P_ * E_ + e0;
#pragma unroll 14
    for (int p = 0; p < P_; ++p) {
        const float4 v = *(const float4*)(base + (size_t)p * E_);
        const float ap = al[p];
        ax += ap * v.x; ay += ap * v.y; az += ap * v.z; aw += ap * v.w;
    }
    float4 sv; sv.x = ax; sv.y = ay; sv.z = az; sv.w = aw;
    *(float4*)(out + (size_t)b * E_ + e0) = sv;
}

// ---------------------------------------------------------------------------
extern "C" void kernel_launch(void* const* d_in, const int* in_sizes, int n_in,
                              void* d_out, int out_size, void* d_ws,
                              size_t ws_size, hipStream_t stream) {
    const float* enc   = (const float*)d_in[0];
    const float* dh    = (const float*)d_in[1];
    const float* wenc  = (const float*)d_in[2];
    const float* benc  = (const float*)d_in[3];
    const float* wdec  = (const float*)d_in[4];
    const float* bdec  = (const float*)d_in[5];
    const float* wfull = (const float*)d_in[6];
    // d_in[7] = b_full: softmax shift-invariant, unused
    float* out = (float*)d_out;

    float* att2p  = out;                              // bytes [0, 524288)
    float* scores = (float*)((char*)d_out + 524288);  // bytes [524288, 624640)

    k_att2<<<dim3(8, B_), 256, 0, stream>>>(dh, wdec, benc, bdec, scores,
                                            att2p);
    k_gemm_scores<<<dim3(4, M_ / 128), 256, 0, stream>>>(enc, wenc, att2p,
                                                         wfull, scores);
    k_softmax<<<B_, 256, 0, stream>>>(scores, out);
    k_context<<<dim3(2, B_), 256, 0, stream>>>(enc, out);
}